// Round 9
// baseline (3909.273 us; speedup 1.0000x reference)
//
#include <hip/hip_runtime.h>
#include <math.h>

#define S_LEN 512
#define D_DIM 256
#define SLICE (S_LEN * D_DIM)   // 131072

typedef _Float16 half8  __attribute__((ext_vector_type(8)));
typedef _Float16 half4v __attribute__((ext_vector_type(4)));
typedef float   floatx4 __attribute__((ext_vector_type(4)));

// ---------------------------------------------------------------------------
// WlhT[d][e] = fp16(Wl[e][d] + (e==d))     (raw + raw@Wl == raw@(I+Wl))
// ---------------------------------------------------------------------------
__global__ __launch_bounds__(256) void prep_wl(const float* __restrict__ Wl,
                                               _Float16* __restrict__ WlhT)
{
    const int d = blockIdx.x, e = threadIdx.x;
    float v = Wl[e * D_DIM + d] + (e == d ? 1.0f : 0.0f);
    WlhT[d * D_DIM + e] = (_Float16)v;
}

// ---------------------------------------------------------------------------
// fp32 -> fp16 copies of k and q (post-linres)
// ---------------------------------------------------------------------------
__global__ __launch_bounds__(256) void cvt_fp16(const float* __restrict__ kf,
                                                const float* __restrict__ qf,
                                                _Float16* __restrict__ kh,
                                                _Float16* __restrict__ qh)
{
    const int i = (blockIdx.x * 256 + threadIdx.x) * 4;
    float4 a = *(const float4*)(kf + i);
    float4 b = *(const float4*)(qf + i);
    half4v ah = { (_Float16)a.x, (_Float16)a.y, (_Float16)a.z, (_Float16)a.w };
    half4v bh = { (_Float16)b.x, (_Float16)b.y, (_Float16)b.z, (_Float16)b.w };
    *(half4v*)(kh + i) = ah;
    *(half4v*)(qh + i) = bh;
}

// ---------------------------------------------------------------------------
// y = x + x@W + b  for [512,256]@[256,256]; 4 rows per block (fp32, small).
// ---------------------------------------------------------------------------
__global__ __launch_bounds__(256) void linres3(
    const float* __restrict__ xk, const float* __restrict__ Wk,
    const float* __restrict__ bk, float* __restrict__ yk,
    const float* __restrict__ xq, const float* __restrict__ Wq,
    const float* __restrict__ bq, float* __restrict__ yq,
    const float* __restrict__ xv, const float* __restrict__ Wv,
    const float* __restrict__ bv, float* __restrict__ yv)
{
    __shared__ float xs[4][D_DIM];
    const int r0 = blockIdx.x * 4;
    const int sel = blockIdx.y;
    const float* x = sel == 0 ? xk : (sel == 1 ? xq : xv);
    const float* W = sel == 0 ? Wk : (sel == 1 ? Wq : Wv);
    const float* b = sel == 0 ? bk : (sel == 1 ? bq : bv);
    float*       y = sel == 0 ? yk : (sel == 1 ? yq : yv);

    const int tid = threadIdx.x;
    #pragma unroll
    for (int t = 0; t < 4; ++t) xs[t][tid] = x[(r0 + t) * D_DIM + tid];
    __syncthreads();
    const float bv_ = b[tid];
    float acc[4];
    #pragma unroll
    for (int i = 0; i < 4; ++i) acc[i] = xs[i][tid] + bv_;
    #pragma unroll 4
    for (int e = 0; e < D_DIM; ++e) {
        const float w = W[e * D_DIM + tid];
        #pragma unroll
        for (int i = 0; i < 4; ++i) acc[i] += xs[i][e] * w;
    }
    #pragma unroll
    for (int i = 0; i < 4; ++i) y[(r0 + i) * D_DIM + tid] = acc[i];
}

// ---------------------------------------------------------------------------
// Final linear with partial-sum fusion: x = sum_c po[c]; out = x + x@W + b
// ---------------------------------------------------------------------------
__global__ __launch_bounds__(256) void linres_sum(
    const float* __restrict__ po, const float* __restrict__ W,
    const float* __restrict__ b, float* __restrict__ y)
{
    __shared__ float xs[4][D_DIM];
    const int tid = threadIdx.x;
    const int r0  = blockIdx.x * 4;
    #pragma unroll
    for (int t = 0; t < 4; ++t) {
        float s = 0.f;
        #pragma unroll
        for (int c = 0; c < 16; ++c)
            s += po[(size_t)c * SLICE + (r0 + t) * D_DIM + tid];
        xs[t][tid] = s;
    }
    __syncthreads();
    const float bv_ = b[tid];
    float acc[4];
    #pragma unroll
    for (int i = 0; i < 4; ++i) acc[i] = xs[i][tid] + bv_;
    #pragma unroll 4
    for (int e = 0; e < D_DIM; ++e) {
        const float w = W[e * D_DIM + tid];
        #pragma unroll
        for (int i = 0; i < 4; ++i) acc[i] += xs[i][e] * w;
    }
    #pragma unroll
    for (int i = 0; i < 4; ++i) y[(r0 + i) * D_DIM + tid] = acc[i];
}

// ---------------------------------------------------------------------------
// Stage 64x256 fp16 q tile into fragment-major LDS (R3/R7-proven):
// fb = mt*8+kk; slot = quad*16+l16; addr16 = fb*64 + slot. Conflict-free.
// ---------------------------------------------------------------------------
__device__ __forceinline__ void stage_q(const _Float16* __restrict__ qh,
                                        _Float16* __restrict__ Afrag,
                                        int sq0, int tid)
{
    const int i   = tid & 63;   // row within tile
    const int qtr = tid >> 6;   // e-quarter (64 elems)
    const int mt = i >> 4, l16 = i & 15;
    const half8* src = (const half8*)(qh + (size_t)(sq0 + i) * D_DIM + qtr * 64);
    #pragma unroll
    for (int u = 0; u < 8; ++u) {
        const int eb   = qtr * 8 + u;           // e-block (8 halfs) 0..31
        const int kk   = eb >> 2, quad = eb & 3;
        const int addr16 = (mt * 8 + kk) * 64 + quad * 16 + l16;
        *(half8*)(Afrag + addr16 * 8) = src[u];
    }
}

// Same layout for a 32-row tile (mt in {0,1}), 4 half8 per thread (R8-proven).
__device__ __forceinline__ void stage_q32(const _Float16* __restrict__ qh,
                                          _Float16* __restrict__ Afrag,
                                          int sq0, int tid)
{
    const int i   = tid & 31;   // row within tile
    const int oct = tid >> 5;   // e-eighth (32 halfs)
    const int mt = i >> 4, l16 = i & 15;
    const half8* src = (const half8*)(qh + (size_t)(sq0 + i) * D_DIM);
    #pragma unroll
    for (int u = 0; u < 4; ++u) {
        const int eb   = oct * 4 + u;           // e-block (8 halfs) 0..31
        const int kk   = eb >> 2, quad = eb & 3;
        const int addr16 = (mt * 8 + kk) * 64 + quad * 16 + l16;
        *(half8*)(Afrag + addr16 * 8) = src[eb];
    }
}

// ---------------------------------------------------------------------------
// Stats (R7 verbatim): per-(sk,d) tile-partial (max, sum |L| e^(L-max)) over
// 64 sq rows. Grid (8 sq-tiles, 2 d-halves, 64 sk-chunks of 8).
// ---------------------------------------------------------------------------
__global__ __launch_bounds__(256, 2) void stats_mfma(
    const _Float16* __restrict__ qh, const _Float16* __restrict__ kh,
    const _Float16* __restrict__ WlhT, const float* __restrict__ bl,
    float* __restrict__ pm, float* __restrict__ ps)
{
    __shared__ _Float16 Afrag[32 * 64 * 8];   // 32 KB

    const int tid  = threadIdx.x;
    const int lane = tid & 63, wave = tid >> 6;
    const int quad = lane >> 4, l16 = lane & 15;
    const int sqt  = blockIdx.x, sq0 = sqt * 64;
    const int dw   = blockIdx.y * 128 + wave * 32;
    const int sk0  = blockIdx.z * 8;

    stage_q(qh, Afrag, sq0, tid);

    half8 wl[2][8];
    #pragma unroll
    for (int nt = 0; nt < 2; ++nt) {
        const int d = dw + nt * 16 + l16;
        #pragma unroll
        for (int kk = 0; kk < 8; ++kk)
            wl[nt][kk] = *(const half8*)(WlhT + (size_t)d * D_DIM + kk * 32 + quad * 8);
    }
    float bl_r[2];
    #pragma unroll
    for (int nt = 0; nt < 2; ++nt)
        bl_r[nt] = bl[dw + nt * 16 + l16];

    __syncthreads();

    #pragma unroll 1
    for (int s = 0; s < 8; ++s) {
        const int sk = sk0 + s;
        floatx4 acc[4][2];
        #pragma unroll
        for (int mt = 0; mt < 4; ++mt)
            #pragma unroll
            for (int nt = 0; nt < 2; ++nt)
                acc[mt][nt] = (floatx4){0.f, 0.f, 0.f, 0.f};

        #pragma unroll 2
        for (int kk = 0; kk < 8; ++kk) {
            const half8 k8 = *(const half8*)(kh + (size_t)sk * D_DIM + kk * 32 + quad * 8);
            half8 af[4], bf[2];
            #pragma unroll
            for (int mt = 0; mt < 4; ++mt)
                af[mt] = *(const half8*)(Afrag + ((mt * 8 + kk) * 64 + lane) * 8);
            #pragma unroll
            for (int nt = 0; nt < 2; ++nt)
                bf[nt] = wl[nt][kk] * k8;
            #pragma unroll
            for (int mt = 0; mt < 4; ++mt)
                #pragma unroll
                for (int nt = 0; nt < 2; ++nt)
                    acc[mt][nt] = __builtin_amdgcn_mfma_f32_16x16x32_f16(
                        af[mt], bf[nt], acc[mt][nt], 0, 0, 0);
        }

        #pragma unroll
        for (int nt = 0; nt < 2; ++nt) {
            float Lv[4][4];
            float tmax = -1e30f;
            #pragma unroll
            for (int mt = 0; mt < 4; ++mt)
                #pragma unroll
                for (int r = 0; r < 4; ++r) {
                    const float L = acc[mt][nt][r] + bl_r[nt];
                    Lv[mt][r] = L;
                    tmax = fmaxf(tmax, L);
                }
            float tsum = 0.f;
            #pragma unroll
            for (int mt = 0; mt < 4; ++mt)
                #pragma unroll
                for (int r = 0; r < 4; ++r)
                    tsum += fabsf(Lv[mt][r]) * __expf(Lv[mt][r] - tmax);

            float m = tmax, ss = tsum;
            #pragma unroll
            for (int mask = 16; mask <= 32; mask <<= 1) {
                float m2 = __shfl_xor(m, mask, 64);
                float s2 = __shfl_xor(ss, mask, 64);
                float M  = fmaxf(m, m2);
                ss = ss * __expf(m - M) + s2 * __expf(m2 - M);
                m = M;
            }
            if (quad == 0) {
                const int d = dw + nt * 16 + l16;
                pm[((size_t)sqt * S_LEN + sk) * D_DIM + d] = m;
                ps[((size_t)sqt * S_LEN + sk) * D_DIM + d] = ss;
            }
        }
    }
}

// ---------------------------------------------------------------------------
// Merge the 8 sq-tile partials; fold epilogue constants:
// msv[sk,d] = { bl-m, v/(S+1) }
// ---------------------------------------------------------------------------
__global__ __launch_bounds__(256) void reduce_ms(
    const float* __restrict__ pm, const float* __restrict__ ps,
    const float* __restrict__ vbuf, const float* __restrict__ bl,
    float2* __restrict__ msv)
{
    const int idx = blockIdx.x * 256 + threadIdx.x;   // sk*256 + d
    float m = pm[idx], ss = ps[idx];
    #pragma unroll
    for (int t = 1; t < 8; ++t) {
        const float m2 = pm[t * SLICE + idx];
        const float s2 = ps[t * SLICE + idx];
        const float M  = fmaxf(m, m2);
        ss = ss * __expf(m - M) + s2 * __expf(m2 - M);
        m = M;
    }
    msv[idx] = make_float2(bl[idx & 255] - m, vbuf[idx] / (ss + 1.0f));
}

// ---------------------------------------------------------------------------
// Accum: recompute L' via MFMA, o += (L'+bl)*c.y * e^(L'+c.x) over 32 sk;
// plain stores of the 32x64 partial tile to po[chunk] (no atomics).
// Grid (16 sq-tiles of 32, 4 d-quarters of 64, 16 sk-chunks of 32) = 1024.
// Wave tile: 32 sq x 16 d (mt=2, nt=1): wl[8]=32 VGPR, acc+o=16 VGPR.
// ---------------------------------------------------------------------------
__global__ __launch_bounds__(256, 2) void accum_mfma(
    const _Float16* __restrict__ qh, const _Float16* __restrict__ kh,
    const _Float16* __restrict__ WlhT, const float* __restrict__ bl,
    const float2* __restrict__ msv, float* __restrict__ po)
{
    __shared__ _Float16 Afrag[16 * 64 * 8];   // 16 KB

    const int tid  = threadIdx.x;
    const int lane = tid & 63, wave = tid >> 6;
    const int quad = lane >> 4, l16 = lane & 15;
    const int sq0  = blockIdx.x * 32;
    const int dw   = blockIdx.y * 64 + wave * 16;
    const int chunk = blockIdx.z;
    const int sk0  = chunk * 32;

    stage_q32(qh, Afrag, sq0, tid);

    half8 wl[8];
    {
        const int d = dw + l16;
        #pragma unroll
        for (int kk = 0; kk < 8; ++kk)
            wl[kk] = *(const half8*)(WlhT + (size_t)d * D_DIM + kk * 32 + quad * 8);
    }
    const float blv = bl[dw + l16];

    floatx4 o[2];
    o[0] = (floatx4){0.f, 0.f, 0.f, 0.f};
    o[1] = (floatx4){0.f, 0.f, 0.f, 0.f};

    __syncthreads();

    #pragma unroll 1
    for (int s = 0; s < 32; ++s) {
        const int sk = sk0 + s;
        floatx4 acc[2];
        acc[0] = (floatx4){0.f, 0.f, 0.f, 0.f};
        acc[1] = (floatx4){0.f, 0.f, 0.f, 0.f};

        #pragma unroll 2
        for (int kk = 0; kk < 8; ++kk) {
            const half8 k8 = *(const half8*)(kh + (size_t)sk * D_DIM + kk * 32 + quad * 8);
            const half8 bf = wl[kk] * k8;
            half8 af0 = *(const half8*)(Afrag + ((0 * 8 + kk) * 64 + lane) * 8);
            half8 af1 = *(const half8*)(Afrag + ((1 * 8 + kk) * 64 + lane) * 8);
            acc[0] = __builtin_amdgcn_mfma_f32_16x16x32_f16(af0, bf, acc[0], 0, 0, 0);
            acc[1] = __builtin_amdgcn_mfma_f32_16x16x32_f16(af1, bf, acc[1], 0, 0, 0);
        }

        const float2 c = msv[((size_t)sk << 8) + dw + l16];
        #pragma unroll
        for (int mt = 0; mt < 2; ++mt)
            #pragma unroll
            for (int r = 0; r < 4; ++r) {
                const float Lp = acc[mt][r];
                const float e  = __expf(Lp + c.x);     // e^(L-m)
                const float u  = (Lp + blv) * c.y;     // L * v/(S+1)
                o[mt][r] = fmaf(u, e, o[mt][r]);
            }
    }

    float* dst = po + (size_t)chunk * SLICE;
    #pragma unroll
    for (int mt = 0; mt < 2; ++mt)
        #pragma unroll
        for (int r = 0; r < 4; ++r) {
            const int row = sq0 + mt * 16 + quad * 4 + r;
            const int col = dw + l16;
            dst[(size_t)row * D_DIM + col] = o[mt][r];
        }
}

// ---------------------------------------------------------------------------
extern "C" void kernel_launch(void* const* d_in, const int* in_sizes, int n_in,
                              void* d_out, int out_size, void* d_ws, size_t ws_size,
                              hipStream_t stream)
{
    const float* query = (const float*)d_in[0];
    const float* key   = (const float*)d_in[1];
    const float* value = (const float*)d_in[2];
    const float* Wk  = (const float*)d_in[3];
    const float* bk  = (const float*)d_in[4];
    const float* Wq  = (const float*)d_in[5];
    const float* bq  = (const float*)d_in[6];
    const float* Wva = (const float*)d_in[7];
    const float* bva = (const float*)d_in[8];
    const float* Wl  = (const float*)d_in[9];
    const float* bl  = (const float*)d_in[10];
    const float* Wvo = (const float*)d_in[11];
    const float* bvo = (const float*)d_in[12];

    const int MAT = SLICE;                    // 131072
    float* ws   = (float*)d_ws;
    // Same overall footprint as the R7-proven layout (12.2 MB).
    float* kbuf = ws;
    float* qbuf = ws + MAT;
    float* vbuf = ws + 2 * MAT;
    float2* msv = (float2*)(ws + 3 * MAT);                 // 2 slots (1 MB)
    _Float16* WlhT = (_Float16*)(ws + 6 * MAT);            // 128 KB
    _Float16* kh   = (_Float16*)(ws + 6 * MAT + 32768);    // 256 KB
    _Float16* qh   = kh + MAT;                             // 256 KB
    float* pm  = ws + 6 * MAT + 32768 + 2 * 65536;         // 4 MB
    float* ps  = pm + 8 * MAT;                             // 4 MB
    float* po  = pm;   // accum partials reuse pm+ps (dead after reduce_ms): 16*MAT
    float* out = (float*)d_out;

    prep_wl<<<256, 256, 0, stream>>>(Wl, WlhT);
    linres3<<<dim3(128, 3), 256, 0, stream>>>(key, Wk, bk, kbuf,
                                              query, Wq, bq, qbuf,
                                              value, Wva, bva, vbuf);
    cvt_fp16<<<128, 256, 0, stream>>>(kbuf, qbuf, kh, qh);

    stats_mfma<<<dim3(8, 2, 64), 256, 0, stream>>>(qh, kh, WlhT, bl, pm, ps);
    reduce_ms<<<512, 256, 0, stream>>>(pm, ps, vbuf, bl, msv);
    accum_mfma<<<dim3(16, 4, 16), 256, 0, stream>>>(qh, kh, WlhT, bl, msv, po);

    linres_sum<<<128, 256, 0, stream>>>(po, Wvo, bvo, out);
}

// Round 11
// 279.729 us; speedup vs baseline: 13.9752x; 13.9752x over previous
//
#include <hip/hip_runtime.h>
#include <math.h>

#define S_LEN 512
#define D_DIM 256

typedef _Float16 half8  __attribute__((ext_vector_type(8)));
typedef _Float16 half4v __attribute__((ext_vector_type(4)));
typedef float   floatx4 __attribute__((ext_vector_type(4)));

// ---------------------------------------------------------------------------
// WlhT[d][e] = fp16(Wl[e][d] + (e==d))     (raw + raw@Wl == raw@(I+Wl))
// ---------------------------------------------------------------------------
__global__ __launch_bounds__(256) void prep_wl(const float* __restrict__ Wl,
                                               _Float16* __restrict__ WlhT)
{
    const int d = blockIdx.x, e = threadIdx.x;
    float v = Wl[e * D_DIM + d] + (e == d ? 1.0f : 0.0f);
    WlhT[d * D_DIM + e] = (_Float16)v;
}

// ---------------------------------------------------------------------------
// fp32 -> fp16 copies of k and q (post-linres)
// ---------------------------------------------------------------------------
__global__ __launch_bounds__(256) void cvt_fp16(const float* __restrict__ kf,
                                                const float* __restrict__ qf,
                                                _Float16* __restrict__ kh,
                                                _Float16* __restrict__ qh)
{
    const int i = (blockIdx.x * 256 + threadIdx.x) * 4;
    float4 a = *(const float4*)(kf + i);
    float4 b = *(const float4*)(qf + i);
    half4v ah = { (_Float16)a.x, (_Float16)a.y, (_Float16)a.z, (_Float16)a.w };
    half4v bh = { (_Float16)b.x, (_Float16)b.y, (_Float16)b.z, (_Float16)b.w };
    *(half4v*)(kh + i) = ah;
    *(half4v*)(qh + i) = bh;
}

// ---------------------------------------------------------------------------
// y = x + x@W + b  for [512,256]@[256,256]; 4 rows per block (fp32, small).
// ---------------------------------------------------------------------------
__device__ __forceinline__ void linres_body(const float* __restrict__ x,
                                            const float* __restrict__ W,
                                            const float* __restrict__ b,
                                            float* __restrict__ y, int r0)
{
    __shared__ float xs[4][D_DIM];
    const int tid = threadIdx.x;
    #pragma unroll
    for (int t = 0; t < 4; ++t) xs[t][tid] = x[(r0 + t) * D_DIM + tid];
    __syncthreads();
    const float bv = b[tid];
    float acc[4];
    #pragma unroll
    for (int i = 0; i < 4; ++i) acc[i] = xs[i][tid] + bv;
    #pragma unroll 4
    for (int e = 0; e < D_DIM; ++e) {
        const float w = W[e * D_DIM + tid];
        #pragma unroll
        for (int i = 0; i < 4; ++i) acc[i] += xs[i][e] * w;
    }
    #pragma unroll
    for (int i = 0; i < 4; ++i) y[(r0 + i) * D_DIM + tid] = acc[i];
}

__global__ __launch_bounds__(256) void linres3(
    const float* __restrict__ xk, const float* __restrict__ Wk,
    const float* __restrict__ bk, float* __restrict__ yk,
    const float* __restrict__ xq, const float* __restrict__ Wq,
    const float* __restrict__ bq, float* __restrict__ yq,
    const float* __restrict__ xv, const float* __restrict__ Wv,
    const float* __restrict__ bv, float* __restrict__ yv)
{
    const int r0 = blockIdx.x * 4;
    const int sel = blockIdx.y;
    const float* x = sel == 0 ? xk : (sel == 1 ? xq : xv);
    const float* W = sel == 0 ? Wk : (sel == 1 ? Wq : Wv);
    const float* b = sel == 0 ? bk : (sel == 1 ? bq : bv);
    float*       y = sel == 0 ? yk : (sel == 1 ? yq : yv);
    linres_body(x, W, b, y, r0);
}

__global__ __launch_bounds__(256) void linres1(
    const float* __restrict__ x, const float* __restrict__ W,
    const float* __restrict__ b, float* __restrict__ y)
{
    linres_body(x, W, b, y, blockIdx.x * 4);
}

// ---------------------------------------------------------------------------
// Stage 64x256 fp16 q tile into fragment-major LDS (R3/R7-proven):
// fb = mt*8+kk; slot = quad*16+l16; addr16 = fb*64 + slot. Conflict-free.
// ---------------------------------------------------------------------------
__device__ __forceinline__ void stage_q(const _Float16* __restrict__ qh,
                                        _Float16* __restrict__ Afrag,
                                        int sq0, int tid)
{
    const int i   = tid & 63;   // row within tile
    const int qtr = tid >> 6;   // e-quarter (64 elems)
    const int mt = i >> 4, l16 = i & 15;
    const half8* src = (const half8*)(qh + (size_t)(sq0 + i) * D_DIM + qtr * 64);
    #pragma unroll
    for (int u = 0; u < 8; ++u) {
        const int eb   = qtr * 8 + u;           // e-block (8 halfs) 0..31
        const int kk   = eb >> 2, quad = eb & 3;
        const int addr16 = (mt * 8 + kk) * 64 + quad * 16 + l16;
        *(half8*)(Afrag + addr16 * 8) = src[u];
    }
}

// ---------------------------------------------------------------------------
// Stats: L = q @ (diag(k_sk)(I+Wl)) + bl per sk; per-(sk,d) tile-partial
// (max, sum |L| e^(L-max)) over this block's 64 sq rows -> pm/ps.
// Grid (8 sq-tiles, 2 d-halves, 64 sk-chunks of 8). ONE barrier per block.
// kk loop is FULLY unrolled: wl[nt][kk] indices must be compile-time consts
// so wl stays in VGPRs. (#pragma unroll 2 made wl dynamically-indexed ->
// scratch demotion -> the R7-R9 hidden scratch-latency/traffic bug.)
// ---------------------------------------------------------------------------
__global__ __launch_bounds__(256, 2) void stats_mfma(
    const _Float16* __restrict__ qh, const _Float16* __restrict__ kh,
    const _Float16* __restrict__ WlhT, const float* __restrict__ bl,
    float* __restrict__ pm, float* __restrict__ ps)
{
    __shared__ _Float16 Afrag[32 * 64 * 8];   // 32 KB

    const int tid  = threadIdx.x;
    const int lane = tid & 63, wave = tid >> 6;
    const int quad = lane >> 4, l16 = lane & 15;
    const int sqt  = blockIdx.x, sq0 = sqt * 64;
    const int dw   = blockIdx.y * 128 + wave * 32;
    const int sk0  = blockIdx.z * 8;

    stage_q(qh, Afrag, sq0, tid);

    half8 wl[2][8];
    #pragma unroll
    for (int nt = 0; nt < 2; ++nt) {
        const int d = dw + nt * 16 + l16;
        #pragma unroll
        for (int kk = 0; kk < 8; ++kk)
            wl[nt][kk] = *(const half8*)(WlhT + (size_t)d * D_DIM + kk * 32 + quad * 8);
    }
    float bl_r[2];
    #pragma unroll
    for (int nt = 0; nt < 2; ++nt)
        bl_r[nt] = bl[dw + nt * 16 + l16];

    __syncthreads();

    #pragma unroll 1
    for (int s = 0; s < 8; ++s) {
        const int sk = sk0 + s;
        floatx4 acc[4][2];
        #pragma unroll
        for (int mt = 0; mt < 4; ++mt)
            #pragma unroll
            for (int nt = 0; nt < 2; ++nt)
                acc[mt][nt] = (floatx4){0.f, 0.f, 0.f, 0.f};

        #pragma unroll
        for (int kk = 0; kk < 8; ++kk) {
            const half8 k8 = *(const half8*)(kh + (size_t)sk * D_DIM + kk * 32 + quad * 8);
            half8 af[4], bf[2];
            #pragma unroll
            for (int mt = 0; mt < 4; ++mt)
                af[mt] = *(const half8*)(Afrag + ((mt * 8 + kk) * 64 + lane) * 8);
            #pragma unroll
            for (int nt = 0; nt < 2; ++nt)
                bf[nt] = wl[nt][kk] * k8;
            #pragma unroll
            for (int mt = 0; mt < 4; ++mt)
                #pragma unroll
                for (int nt = 0; nt < 2; ++nt)
                    acc[mt][nt] = __builtin_amdgcn_mfma_f32_16x16x32_f16(
                        af[mt], bf[nt], acc[mt][nt], 0, 0, 0);
        }

        #pragma unroll
        for (int nt = 0; nt < 2; ++nt) {
            float Lv[4][4];
            float tmax = -1e30f;
            #pragma unroll
            for (int mt = 0; mt < 4; ++mt)
                #pragma unroll
                for (int r = 0; r < 4; ++r) {
                    const float L = acc[mt][nt][r] + bl_r[nt];
                    Lv[mt][r] = L;
                    tmax = fmaxf(tmax, L);
                }
            float tsum = 0.f;
            #pragma unroll
            for (int mt = 0; mt < 4; ++mt)
                #pragma unroll
                for (int r = 0; r < 4; ++r)
                    tsum += fabsf(Lv[mt][r]) * __expf(Lv[mt][r] - tmax);

            float m = tmax, ss = tsum;
            #pragma unroll
            for (int mask = 16; mask <= 32; mask <<= 1) {
                float m2 = __shfl_xor(m, mask, 64);
                float s2 = __shfl_xor(ss, mask, 64);
                float M  = fmaxf(m, m2);
                ss = ss * __expf(m - M) + s2 * __expf(m2 - M);
                m = M;
            }
            if (quad == 0) {
                const int d = dw + nt * 16 + l16;
                pm[((size_t)sqt * S_LEN + sk) * D_DIM + d] = m;
                ps[((size_t)sqt * S_LEN + sk) * D_DIM + d] = ss;
            }
        }
    }
}

// ---------------------------------------------------------------------------
// Merge the 8 sq-tile partials -> mbuf, sbuf  (R3/R7-proven)
// ---------------------------------------------------------------------------
__global__ __launch_bounds__(256) void reduce_ms(
    const float* __restrict__ pm, const float* __restrict__ ps,
    float* __restrict__ mbuf, float* __restrict__ sbuf)
{
    const int idx = blockIdx.x * 256 + threadIdx.x;   // (sk,d), 131072 total
    float m = pm[idx], ss = ps[idx];
    #pragma unroll
    for (int t = 1; t < 8; ++t) {
        const float m2 = pm[t * (S_LEN * D_DIM) + idx];
        const float s2 = ps[t * (S_LEN * D_DIM) + idx];
        const float M  = fmaxf(m, m2);
        ss = ss * __expf(m - M) + s2 * __expf(m2 - M);
        m = M;
    }
    mbuf[idx] = m;
    sbuf[idx] = ss;
}

// ---------------------------------------------------------------------------
// Accum: recompute L, p = L e^(L-m) / (S+1); o += v[sk,d]*p over sk;
// one atomicAdd per element. Grid (8 sq-tiles, 2 d-halves, 64 sk-chunks).
// kk loop FULLY unrolled (see stats_mfma comment).
// ---------------------------------------------------------------------------
__global__ __launch_bounds__(256, 2) void accum_mfma(
    const _Float16* __restrict__ qh, const _Float16* __restrict__ kh,
    const _Float16* __restrict__ WlhT, const float* __restrict__ bl,
    const float* __restrict__ mbuf, const float* __restrict__ sbuf,
    const float* __restrict__ vbuf, float* __restrict__ vs)
{
    __shared__ _Float16 Afrag[32 * 64 * 8];   // 32 KB

    const int tid  = threadIdx.x;
    const int lane = tid & 63, wave = tid >> 6;
    const int quad = lane >> 4, l16 = lane & 15;
    const int sq0  = blockIdx.x * 64;
    const int dw   = blockIdx.y * 128 + wave * 32;
    const int sk0  = blockIdx.z * 8;

    stage_q(qh, Afrag, sq0, tid);

    half8 wl[2][8];
    #pragma unroll
    for (int nt = 0; nt < 2; ++nt) {
        const int d = dw + nt * 16 + l16;
        #pragma unroll
        for (int kk = 0; kk < 8; ++kk)
            wl[nt][kk] = *(const half8*)(WlhT + (size_t)d * D_DIM + kk * 32 + quad * 8);
    }
    float bl_r[2];
    #pragma unroll
    for (int nt = 0; nt < 2; ++nt)
        bl_r[nt] = bl[dw + nt * 16 + l16];

    floatx4 o[4][2];
    #pragma unroll
    for (int mt = 0; mt < 4; ++mt)
        #pragma unroll
        for (int nt = 0; nt < 2; ++nt)
            o[mt][nt] = (floatx4){0.f, 0.f, 0.f, 0.f};

    __syncthreads();

    #pragma unroll 1
    for (int s = 0; s < 8; ++s) {
        const int sk = sk0 + s;
        floatx4 acc[4][2];
        #pragma unroll
        for (int mt = 0; mt < 4; ++mt)
            #pragma unroll
            for (int nt = 0; nt < 2; ++nt)
                acc[mt][nt] = (floatx4){0.f, 0.f, 0.f, 0.f};

        #pragma unroll
        for (int kk = 0; kk < 8; ++kk) {
            const half8 k8 = *(const half8*)(kh + (size_t)sk * D_DIM + kk * 32 + quad * 8);
            half8 af[4], bf[2];
            #pragma unroll
            for (int mt = 0; mt < 4; ++mt)
                af[mt] = *(const half8*)(Afrag + ((mt * 8 + kk) * 64 + lane) * 8);
            #pragma unroll
            for (int nt = 0; nt < 2; ++nt)
                bf[nt] = wl[nt][kk] * k8;
            #pragma unroll
            for (int mt = 0; mt < 4; ++mt)
                #pragma unroll
                for (int nt = 0; nt < 2; ++nt)
                    acc[mt][nt] = __builtin_amdgcn_mfma_f32_16x16x32_f16(
                        af[mt], bf[nt], acc[mt][nt], 0, 0, 0);
        }

        #pragma unroll
        for (int nt = 0; nt < 2; ++nt) {
            const int d = dw + nt * 16 + l16;
            const float m_r = mbuf[(size_t)sk * D_DIM + d];
            const float inv = 1.0f / (sbuf[(size_t)sk * D_DIM + d] + 1.0f);
            const float vv  = vbuf[(size_t)sk * D_DIM + d];
            #pragma unroll
            for (int mt = 0; mt < 4; ++mt)
                #pragma unroll
                for (int r = 0; r < 4; ++r) {
                    const float L = acc[mt][nt][r] + bl_r[nt];
                    const float p = L * __expf(L - m_r) * inv;
                    o[mt][nt][r] += vv * p;
                }
        }
    }

    #pragma unroll
    for (int mt = 0; mt < 4; ++mt)
        #pragma unroll
        for (int nt = 0; nt < 2; ++nt)
            #pragma unroll
            for (int r = 0; r < 4; ++r) {
                const int row = sq0 + mt * 16 + quad * 4 + r;
                const int col = dw + nt * 16 + l16;
                atomicAdd(&vs[(size_t)row * D_DIM + col], o[mt][nt][r]);
            }
}

// ---------------------------------------------------------------------------
extern "C" void kernel_launch(void* const* d_in, const int* in_sizes, int n_in,
                              void* d_out, int out_size, void* d_ws, size_t ws_size,
                              hipStream_t stream)
{
    const float* query = (const float*)d_in[0];
    const float* key   = (const float*)d_in[1];
    const float* value = (const float*)d_in[2];
    const float* Wk  = (const float*)d_in[3];
    const float* bk  = (const float*)d_in[4];
    const float* Wq  = (const float*)d_in[5];
    const float* bq  = (const float*)d_in[6];
    const float* Wva = (const float*)d_in[7];
    const float* bva = (const float*)d_in[8];
    const float* Wl  = (const float*)d_in[9];
    const float* bl  = (const float*)d_in[10];
    const float* Wvo = (const float*)d_in[11];
    const float* bvo = (const float*)d_in[12];

    const int MAT = S_LEN * D_DIM;            // 131072
    float* ws   = (float*)d_ws;
    float* kbuf = ws;
    float* qbuf = ws + MAT;
    float* vbuf = ws + 2 * MAT;
    float* mbuf = ws + 3 * MAT;
    float* sbuf = ws + 4 * MAT;
    float* vs   = ws + 5 * MAT;
    _Float16* WlhT = (_Float16*)(ws + 6 * MAT);            // 128 KB
    _Float16* kh   = (_Float16*)(ws + 6 * MAT + 32768);    // 256 KB
    _Float16* qh   = kh + MAT;                             // 256 KB
    float* pm  = ws + 6 * MAT + 32768 + 2 * 65536;         // 4 MB
    float* ps  = pm + 8 * MAT;                             // 4 MB
    float* out = (float*)d_out;

    prep_wl<<<256, 256, 0, stream>>>(Wl, WlhT);
    linres3<<<dim3(128, 3), 256, 0, stream>>>(key, Wk, bk, kbuf,
                                              query, Wq, bq, qbuf,
                                              value, Wva, bva, vbuf);
    cvt_fp16<<<128, 256, 0, stream>>>(kbuf, qbuf, kh, qh);
    hipMemsetAsync(vs, 0, MAT * sizeof(float), stream);

    stats_mfma<<<dim3(8, 2, 64), 256, 0, stream>>>(qh, kh, WlhT, bl, pm, ps);
    reduce_ms<<<512, 256, 0, stream>>>(pm, ps, mbuf, sbuf);
    accum_mfma<<<dim3(8, 2, 64), 256, 0, stream>>>(qh, kh, WlhT, bl,
                                                   mbuf, sbuf, vbuf, vs);

    linres1<<<128, 256, 0, stream>>>(vs, Wvo, bvo, out);
}

// Round 12
// 218.269 us; speedup vs baseline: 17.9104x; 1.2816x over previous
//
#include <hip/hip_runtime.h>
#include <math.h>

#define S_LEN 512
#define D_DIM 256
#define SLICE (S_LEN * D_DIM)   // 131072

typedef _Float16 half8  __attribute__((ext_vector_type(8)));
typedef _Float16 half4v __attribute__((ext_vector_type(4)));
typedef float   floatx4 __attribute__((ext_vector_type(4)));

// ---------------------------------------------------------------------------
// WlhT[d][e] = fp16(Wl[e][d] + (e==d))     (raw + raw@Wl == raw@(I+Wl))
// ---------------------------------------------------------------------------
__global__ __launch_bounds__(256) void prep_wl(const float* __restrict__ Wl,
                                               _Float16* __restrict__ WlhT)
{
    const int d = blockIdx.x, e = threadIdx.x;
    float v = Wl[e * D_DIM + d] + (e == d ? 1.0f : 0.0f);
    WlhT[d * D_DIM + e] = (_Float16)v;
}

// ---------------------------------------------------------------------------
// fp32 -> fp16 copies of k and q (post-linres)
// ---------------------------------------------------------------------------
__global__ __launch_bounds__(256) void cvt_fp16(const float* __restrict__ kf,
                                                const float* __restrict__ qf,
                                                _Float16* __restrict__ kh,
                                                _Float16* __restrict__ qh)
{
    const int i = (blockIdx.x * 256 + threadIdx.x) * 4;
    float4 a = *(const float4*)(kf + i);
    float4 b = *(const float4*)(qf + i);
    half4v ah = { (_Float16)a.x, (_Float16)a.y, (_Float16)a.z, (_Float16)a.w };
    half4v bh = { (_Float16)b.x, (_Float16)b.y, (_Float16)b.z, (_Float16)b.w };
    *(half4v*)(kh + i) = ah;
    *(half4v*)(qh + i) = bh;
}

// ---------------------------------------------------------------------------
// y = x + x@W + b  for [512,256]@[256,256]; 4 rows per block (fp32, small).
// ---------------------------------------------------------------------------
__global__ __launch_bounds__(256) void linres3(
    const float* __restrict__ xk, const float* __restrict__ Wk,
    const float* __restrict__ bk, float* __restrict__ yk,
    const float* __restrict__ xq, const float* __restrict__ Wq,
    const float* __restrict__ bq, float* __restrict__ yq,
    const float* __restrict__ xv, const float* __restrict__ Wv,
    const float* __restrict__ bv, float* __restrict__ yv)
{
    __shared__ float xs[4][D_DIM];
    const int r0 = blockIdx.x * 4;
    const int sel = blockIdx.y;
    const float* x = sel == 0 ? xk : (sel == 1 ? xq : xv);
    const float* W = sel == 0 ? Wk : (sel == 1 ? Wq : Wv);
    const float* b = sel == 0 ? bk : (sel == 1 ? bq : bv);
    float*       y = sel == 0 ? yk : (sel == 1 ? yq : yv);

    const int tid = threadIdx.x;
    #pragma unroll
    for (int t = 0; t < 4; ++t) xs[t][tid] = x[(r0 + t) * D_DIM + tid];
    __syncthreads();
    const float bv_ = b[tid];
    float acc[4];
    #pragma unroll
    for (int i = 0; i < 4; ++i) acc[i] = xs[i][tid] + bv_;
    #pragma unroll 4
    for (int e = 0; e < D_DIM; ++e) {
        const float w = W[e * D_DIM + tid];
        #pragma unroll
        for (int i = 0; i < 4; ++i) acc[i] += xs[i][e] * w;
    }
    #pragma unroll
    for (int i = 0; i < 4; ++i) y[(r0 + i) * D_DIM + tid] = acc[i];
}

// ---------------------------------------------------------------------------
// Final linear with partial-sum fusion: x = sum_c po[c]; out = x + x@W + b
// (machinery proven in R8)
// ---------------------------------------------------------------------------
__global__ __launch_bounds__(256) void linres_sum(
    const float* __restrict__ po, const float* __restrict__ W,
    const float* __restrict__ b, float* __restrict__ y)
{
    __shared__ float xs[4][D_DIM];
    const int tid = threadIdx.x;
    const int r0  = blockIdx.x * 4;
    #pragma unroll
    for (int t = 0; t < 4; ++t) {
        float s = 0.f;
        #pragma unroll
        for (int c = 0; c < 16; ++c)
            s += po[(size_t)c * SLICE + (r0 + t) * D_DIM + tid];
        xs[t][tid] = s;
    }
    __syncthreads();
    const float bv_ = b[tid];
    float acc[4];
    #pragma unroll
    for (int i = 0; i < 4; ++i) acc[i] = xs[i][tid] + bv_;
    #pragma unroll 4
    for (int e = 0; e < D_DIM; ++e) {
        const float w = W[e * D_DIM + tid];
        #pragma unroll
        for (int i = 0; i < 4; ++i) acc[i] += xs[i][e] * w;
    }
    #pragma unroll
    for (int i = 0; i < 4; ++i) y[(r0 + i) * D_DIM + tid] = acc[i];
}

// ---------------------------------------------------------------------------
// Stage 64x256 fp16 q tile into fragment-major LDS (R3/R7/R11-proven):
// fb = mt*8+kk; slot = quad*16+l16; addr16 = fb*64 + slot. Conflict-free.
// ---------------------------------------------------------------------------
__device__ __forceinline__ void stage_q(const _Float16* __restrict__ qh,
                                        _Float16* __restrict__ Afrag,
                                        int sq0, int tid)
{
    const int i   = tid & 63;   // row within tile
    const int qtr = tid >> 6;   // e-quarter (64 elems)
    const int mt = i >> 4, l16 = i & 15;
    const half8* src = (const half8*)(qh + (size_t)(sq0 + i) * D_DIM + qtr * 64);
    #pragma unroll
    for (int u = 0; u < 8; ++u) {
        const int eb   = qtr * 8 + u;           // e-block (8 halfs) 0..31
        const int kk   = eb >> 2, quad = eb & 3;
        const int addr16 = (mt * 8 + kk) * 64 + quad * 16 + l16;
        *(half8*)(Afrag + addr16 * 8) = src[u];
    }
}

// Same layout for a 32-row tile (mt in {0,1}), 4 half8 per thread (R8-proven).
__device__ __forceinline__ void stage_q32(const _Float16* __restrict__ qh,
                                          _Float16* __restrict__ Afrag,
                                          int sq0, int tid)
{
    const int i   = tid & 31;   // row within tile
    const int oct = tid >> 5;   // e-eighth (32 halfs)
    const int mt = i >> 4, l16 = i & 15;
    const half8* src = (const half8*)(qh + (size_t)(sq0 + i) * D_DIM);
    #pragma unroll
    for (int u = 0; u < 4; ++u) {
        const int eb   = oct * 4 + u;           // e-block (8 halfs) 0..31
        const int kk   = eb >> 2, quad = eb & 3;
        const int addr16 = (mt * 8 + kk) * 64 + quad * 16 + l16;
        *(half8*)(Afrag + addr16 * 8) = src[eb];
    }
}

// ---------------------------------------------------------------------------
// Stats: per-(sk,d) tile-partial (max, sum |L| e^(L-max)) over 64 sq rows.
// Grid (8 sq-tiles, 2 d-halves, 32 sk-chunks of 16). kk loop FULLY unrolled
// (wl must stay in VGPRs — partial unroll demotes it to scratch, the R7-R9 bug).
// ---------------------------------------------------------------------------
__global__ __launch_bounds__(256, 2) void stats_mfma(
    const _Float16* __restrict__ qh, const _Float16* __restrict__ kh,
    const _Float16* __restrict__ WlhT, const float* __restrict__ bl,
    float* __restrict__ pm, float* __restrict__ ps)
{
    __shared__ _Float16 Afrag[32 * 64 * 8];   // 32 KB

    const int tid  = threadIdx.x;
    const int lane = tid & 63, wave = tid >> 6;
    const int quad = lane >> 4, l16 = lane & 15;
    const int sqt  = blockIdx.x, sq0 = sqt * 64;
    const int dw   = blockIdx.y * 128 + wave * 32;
    const int sk0  = blockIdx.z * 16;

    stage_q(qh, Afrag, sq0, tid);

    half8 wl[2][8];
    #pragma unroll
    for (int nt = 0; nt < 2; ++nt) {
        const int d = dw + nt * 16 + l16;
        #pragma unroll
        for (int kk = 0; kk < 8; ++kk)
            wl[nt][kk] = *(const half8*)(WlhT + (size_t)d * D_DIM + kk * 32 + quad * 8);
    }
    float bl_r[2];
    #pragma unroll
    for (int nt = 0; nt < 2; ++nt)
        bl_r[nt] = bl[dw + nt * 16 + l16];

    __syncthreads();

    #pragma unroll 1
    for (int s = 0; s < 16; ++s) {
        const int sk = sk0 + s;
        floatx4 acc[4][2];
        #pragma unroll
        for (int mt = 0; mt < 4; ++mt)
            #pragma unroll
            for (int nt = 0; nt < 2; ++nt)
                acc[mt][nt] = (floatx4){0.f, 0.f, 0.f, 0.f};

        #pragma unroll
        for (int kk = 0; kk < 8; ++kk) {
            const half8 k8 = *(const half8*)(kh + (size_t)sk * D_DIM + kk * 32 + quad * 8);
            half8 af[4], bf[2];
            #pragma unroll
            for (int mt = 0; mt < 4; ++mt)
                af[mt] = *(const half8*)(Afrag + ((mt * 8 + kk) * 64 + lane) * 8);
            #pragma unroll
            for (int nt = 0; nt < 2; ++nt)
                bf[nt] = wl[nt][kk] * k8;
            #pragma unroll
            for (int mt = 0; mt < 4; ++mt)
                #pragma unroll
                for (int nt = 0; nt < 2; ++nt)
                    acc[mt][nt] = __builtin_amdgcn_mfma_f32_16x16x32_f16(
                        af[mt], bf[nt], acc[mt][nt], 0, 0, 0);
        }

        #pragma unroll
        for (int nt = 0; nt < 2; ++nt) {
            float Lv[4][4];
            float tmax = -1e30f;
            #pragma unroll
            for (int mt = 0; mt < 4; ++mt)
                #pragma unroll
                for (int r = 0; r < 4; ++r) {
                    const float L = acc[mt][nt][r] + bl_r[nt];
                    Lv[mt][r] = L;
                    tmax = fmaxf(tmax, L);
                }
            float tsum = 0.f;
            #pragma unroll
            for (int mt = 0; mt < 4; ++mt)
                #pragma unroll
                for (int r = 0; r < 4; ++r)
                    tsum += fabsf(Lv[mt][r]) * __expf(Lv[mt][r] - tmax);

            float m = tmax, ss = tsum;
            #pragma unroll
            for (int mask = 16; mask <= 32; mask <<= 1) {
                float m2 = __shfl_xor(m, mask, 64);
                float s2 = __shfl_xor(ss, mask, 64);
                float M  = fmaxf(m, m2);
                ss = ss * __expf(m - M) + s2 * __expf(m2 - M);
                m = M;
            }
            if (quad == 0) {
                const int d = dw + nt * 16 + l16;
                pm[((size_t)sqt * S_LEN + sk) * D_DIM + d] = m;
                ps[((size_t)sqt * S_LEN + sk) * D_DIM + d] = ss;
            }
        }
    }
}

// ---------------------------------------------------------------------------
// Merge the 8 sq-tile partials -> mbuf, sbuf  (R3/R7/R11-proven)
// ---------------------------------------------------------------------------
__global__ __launch_bounds__(256) void reduce_ms(
    const float* __restrict__ pm, const float* __restrict__ ps,
    float* __restrict__ mbuf, float* __restrict__ sbuf)
{
    const int idx = blockIdx.x * 256 + threadIdx.x;   // (sk,d), 131072 total
    float m = pm[idx], ss = ps[idx];
    #pragma unroll
    for (int t = 1; t < 8; ++t) {
        const float m2 = pm[t * SLICE + idx];
        const float s2 = ps[t * SLICE + idx];
        const float M  = fmaxf(m, m2);
        ss = ss * __expf(m - M) + s2 * __expf(m2 - M);
        m = M;
    }
    mbuf[idx] = m;
    sbuf[idx] = ss;
}

// ---------------------------------------------------------------------------
// Accum: recompute L, p = L e^(L-m)/(S+1); o += v[sk,d]*p over 32 sk;
// PLAIN stores of the 32x128 fp32 partial tile to po[chunk] (no atomics —
// 8.4M device RMW atomics were R7/R11's ~110 us floor).
// Grid (16 sq-tiles of 32, 2 d-halves, 16 sk-chunks of 32) = 512 blocks.
// kk loop FULLY unrolled (wl in VGPRs).
// ---------------------------------------------------------------------------
__global__ __launch_bounds__(256, 2) void accum_mfma(
    const _Float16* __restrict__ qh, const _Float16* __restrict__ kh,
    const _Float16* __restrict__ WlhT, const float* __restrict__ bl,
    const float* __restrict__ mbuf, const float* __restrict__ sbuf,
    const float* __restrict__ vbuf, float* __restrict__ po)
{
    __shared__ _Float16 Afrag[16 * 64 * 8];   // 16 KB

    const int tid  = threadIdx.x;
    const int lane = tid & 63, wave = tid >> 6;
    const int quad = lane >> 4, l16 = lane & 15;
    const int sq0  = blockIdx.x * 32;
    const int dw   = blockIdx.y * 128 + wave * 32;
    const int chunk = blockIdx.z;
    const int sk0  = chunk * 32;

    stage_q32(qh, Afrag, sq0, tid);

    half8 wl[2][8];
    #pragma unroll
    for (int nt = 0; nt < 2; ++nt) {
        const int d = dw + nt * 16 + l16;
        #pragma unroll
        for (int kk = 0; kk < 8; ++kk)
            wl[nt][kk] = *(const half8*)(WlhT + (size_t)d * D_DIM + kk * 32 + quad * 8);
    }
    float bl_r[2];
    #pragma unroll
    for (int nt = 0; nt < 2; ++nt)
        bl_r[nt] = bl[dw + nt * 16 + l16];

    floatx4 o[2][2];
    #pragma unroll
    for (int mt = 0; mt < 2; ++mt)
        #pragma unroll
        for (int nt = 0; nt < 2; ++nt)
            o[mt][nt] = (floatx4){0.f, 0.f, 0.f, 0.f};

    __syncthreads();

    #pragma unroll 1
    for (int s = 0; s < 32; ++s) {
        const int sk = sk0 + s;
        floatx4 acc[2][2];
        #pragma unroll
        for (int mt = 0; mt < 2; ++mt)
            #pragma unroll
            for (int nt = 0; nt < 2; ++nt)
                acc[mt][nt] = (floatx4){0.f, 0.f, 0.f, 0.f};

        #pragma unroll
        for (int kk = 0; kk < 8; ++kk) {
            const half8 k8 = *(const half8*)(kh + (size_t)sk * D_DIM + kk * 32 + quad * 8);
            half8 af[2], bf[2];
            #pragma unroll
            for (int mt = 0; mt < 2; ++mt)
                af[mt] = *(const half8*)(Afrag + ((mt * 8 + kk) * 64 + lane) * 8);
            #pragma unroll
            for (int nt = 0; nt < 2; ++nt)
                bf[nt] = wl[nt][kk] * k8;
            #pragma unroll
            for (int mt = 0; mt < 2; ++mt)
                #pragma unroll
                for (int nt = 0; nt < 2; ++nt)
                    acc[mt][nt] = __builtin_amdgcn_mfma_f32_16x16x32_f16(
                        af[mt], bf[nt], acc[mt][nt], 0, 0, 0);
        }

        #pragma unroll
        for (int nt = 0; nt < 2; ++nt) {
            const int d = dw + nt * 16 + l16;
            const float m_r = mbuf[(size_t)sk * D_DIM + d];
            const float inv = 1.0f / (sbuf[(size_t)sk * D_DIM + d] + 1.0f);
            const float vv  = vbuf[(size_t)sk * D_DIM + d];
            #pragma unroll
            for (int mt = 0; mt < 2; ++mt)
                #pragma unroll
                for (int r = 0; r < 4; ++r) {
                    const float L = acc[mt][nt][r] + bl_r[nt];
                    const float p = L * __expf(L - m_r) * inv;
                    o[mt][nt][r] += vv * p;
                }
        }
    }

    float* dst = po + (size_t)chunk * SLICE;
    #pragma unroll
    for (int mt = 0; mt < 2; ++mt)
        #pragma unroll
        for (int nt = 0; nt < 2; ++nt)
            #pragma unroll
            for (int r = 0; r < 4; ++r) {
                const int row = sq0 + mt * 16 + quad * 4 + r;
                const int col = dw + nt * 16 + l16;
                dst[(size_t)row * D_DIM + col] = o[mt][nt][r];
            }
}

// ---------------------------------------------------------------------------
extern "C" void kernel_launch(void* const* d_in, const int* in_sizes, int n_in,
                              void* d_out, int out_size, void* d_ws, size_t ws_size,
                              hipStream_t stream)
{
    const float* query = (const float*)d_in[0];
    const float* key   = (const float*)d_in[1];
    const float* value = (const float*)d_in[2];
    const float* Wk  = (const float*)d_in[3];
    const float* bk  = (const float*)d_in[4];
    const float* Wq  = (const float*)d_in[5];
    const float* bq  = (const float*)d_in[6];
    const float* Wva = (const float*)d_in[7];
    const float* bva = (const float*)d_in[8];
    const float* Wl  = (const float*)d_in[9];
    const float* bl  = (const float*)d_in[10];
    const float* Wvo = (const float*)d_in[11];
    const float* bvo = (const float*)d_in[12];

    const int MAT = SLICE;                    // 131072
    float* ws   = (float*)d_ws;
    // R11-proven footprint; vs slot now unused, po overlays dead pm+ps.
    float* kbuf = ws;
    float* qbuf = ws + MAT;
    float* vbuf = ws + 2 * MAT;
    float* mbuf = ws + 3 * MAT;
    float* sbuf = ws + 4 * MAT;
    _Float16* WlhT = (_Float16*)(ws + 6 * MAT);            // 128 KB
    _Float16* kh   = (_Float16*)(ws + 6 * MAT + 32768);    // 256 KB
    _Float16* qh   = kh + MAT;                             // 256 KB
    float* pm  = ws + 6 * MAT + 32768 + 2 * 65536;         // 4 MB
    float* ps  = pm + 8 * MAT;                             // 4 MB
    float* po  = pm;   // 16*MAT floats (8 MB), pm/ps dead after reduce_ms
    float* out = (float*)d_out;

    prep_wl<<<256, 256, 0, stream>>>(Wl, WlhT);
    linres3<<<dim3(128, 3), 256, 0, stream>>>(key, Wk, bk, kbuf,
                                              query, Wq, bq, qbuf,
                                              value, Wva, bva, vbuf);
    cvt_fp16<<<128, 256, 0, stream>>>(kbuf, qbuf, kh, qh);

    stats_mfma<<<dim3(8, 2, 32), 256, 0, stream>>>(qh, kh, WlhT, bl, pm, ps);
    reduce_ms<<<512, 256, 0, stream>>>(pm, ps, mbuf, sbuf);
    accum_mfma<<<dim3(16, 2, 16), 256, 0, stream>>>(qh, kh, WlhT, bl,
                                                    mbuf, sbuf, vbuf, po);

    linres_sum<<<128, 256, 0, stream>>>(po, Wvo, bvo, out);
}